// Round 6
// baseline (446.017 us; speedup 1.0000x reference)
//
#include <hip/hip_runtime.h>

// QuadPool — layout (established rounds 0-3, verified passing rounds 4-5):
//   in_sizes = element counts: [N*C f32 features][N int32 keys][P int32 plk]
//   d_out = FLOAT32, out_size = P*C + N: [pooled P*C][parent_idx N]
// pooled[p,:] = max over children whose keys>>2 maps to parent p (keys sorted ->
// contiguous segments); empty parents -> 0. parent_idx[i] = searchsorted(plk, keys[i]>>2).
//
// Round-6 change: SINGLE fused dispatch. The former qp_starts kernel (20-deep
// dependent binary-search chain, ran ~alone in front of the pool stream) is
// folded into each pool wave as a lane-split dual search (lanes<32 find start,
// lanes>=32 find end, broadcast via shfl) that overlaps with other waves'
// feature streaming. pidx blocks ride in the same grid, placed first so they
// don't trail the stream. Saves ~2 launches + ~15 us of serialized front-work.

typedef float v4f __attribute__((ext_vector_type(4)));

static __device__ __forceinline__ v4f vmax4(v4f a, v4f b) {
    v4f r;
    r.x = fmaxf(a.x, b.x); r.y = fmaxf(a.y, b.y);
    r.z = fmaxf(a.z, b.z); r.w = fmaxf(a.w, b.w);
    return r;
}

__global__ void __launch_bounds__(256) qp_fused(const float* __restrict__ feat,
        const int* __restrict__ keys, const int* __restrict__ plk,
        float* __restrict__ outf, int N, int P, int C, int pidxBlocks) {

    if ((int)blockIdx.x < pidxBlocks) {
        // ---- parent_idx path: [P*C .. P*C+N) = searchsorted(plk, keys[i]>>2) ----
        int i = blockIdx.x * 256 + threadIdx.x;
        if (i >= N) return;
        const int pk = keys[i] >> 2;
        int idx;
        if (pk >= 0 && pk < P && plk[pk] == pk && (pk == 0 || plk[pk - 1] < pk)) {
            idx = pk;                            // plk is arange: O(1)
        } else {
            int lo = 0, hi = P;
            while (lo < hi) {
                int mid = (lo + hi) >> 1;
                if (plk[mid] >= pk) hi = mid; else lo = mid + 1;
            }
            idx = lo;
        }
        __builtin_nontemporal_store((float)idx, outf + (size_t)P * C + i);
        return;
    }

    // ---- pool path: one 64-lane wave per parent ----
    int t = (blockIdx.x - pidxBlocks) * 256 + threadIdx.x;
    int wave = t >> 6, lane = t & 63;
    if (wave >= P) return;

    // Segment bounds via lane-split dual binary search over keys (L2-resident):
    //   bound(target) = first i with (keys[i]>>2) > target
    //   s = bound(plk[wave-1])  (or 0: target=-1 gives lo=0),  e = bound(plk[wave])
    const int t_lo = (wave == 0) ? -1 : plk[wave - 1];
    const int t_hi = plk[wave];
    const int target = (lane & 32) ? t_hi : t_lo;
    int lo = 0, hi = N;
    while (lo < hi) {
        int mid = (lo + hi) >> 1;
        if ((keys[mid] >> 2) > target) hi = mid; else lo = mid + 1;
    }
    const int s = __shfl(lo, 0, 64);
    const int e = __shfl(lo, 32, 64);
    const int n = e - s;

    // Lane l owns channels [4l,4l+4): 64 lanes x 16B = 1KB coalesced row reads;
    // consecutive waves own consecutive row ranges -> feat is one pure stream.
    const size_t stepv = (size_t)(C >> 2);
    for (int c0 = lane * 4; c0 < C; c0 += 256) {
        const v4f* p = reinterpret_cast<const v4f*>(feat + (size_t)s * C + c0);
        v4f m; m.x = m.y = m.z = m.w = -INFINITY;
        int i = 0;
        for (; i + 2 <= n; i += 2) {             // 2 loads in flight per wave
            v4f a = __builtin_nontemporal_load(p);
            v4f b = __builtin_nontemporal_load(p + stepv);
            p += 2 * stepv;
            m = vmax4(m, vmax4(a, b));
        }
        if (i < n) m = vmax4(m, __builtin_nontemporal_load(p));
        if (n <= 0) { m.x = m.y = m.z = m.w = 0.f; }   // empty parent -> 0
        __builtin_nontemporal_store(m,
            reinterpret_cast<v4f*>(outf + (size_t)wave * C + c0));
    }
}

extern "C" void kernel_launch(void* const* d_in, const int* in_sizes, int n_in,
                              void* d_out, int out_size, void* d_ws, size_t ws_size,
                              hipStream_t stream) {
    const float* feat = (const float*)d_in[0];
    const int*   keys = (const int*)d_in[1];
    const int*   plk  = (const int*)d_in[2];

    // Geometry (validated against out_size invariant; (1,1) is the known-true case).
    const long long F = in_sizes[0], K = in_sizes[1], L = in_sizes[2];
    int N = (int)K, P = (int)L, C = (int)(F / (K > 0 ? K : 1));
    if ((long long)P * C + N != (long long)out_size) {
        for (int w1 = 1; w1 <= 2; ++w1) {
            bool done = false;
            for (int w2 = 1; w2 <= 2; ++w2) {
                if (K % w1 || L % w2) continue;
                long long n = K / w1, p = L / w2;
                if (n <= 0 || p <= 0 || F % n) continue;
                long long c = F / n;
                if (p * c + n == (long long)out_size) {
                    N = (int)n; P = (int)p; C = (int)c; done = true; break;
                }
            }
            if (done) break;
        }
    }

    const int tb = 256;
    const int pidxBlocks = (N + tb - 1) / tb;
    const long long poolThreads = (long long)P * 64;
    const int poolBlocks = (int)((poolThreads + tb - 1) / tb);
    qp_fused<<<pidxBlocks + poolBlocks, tb, 0, stream>>>(
        feat, keys, plk, (float*)d_out, N, P, C, pidxBlocks);
}

// Round 7
// 224.226 us; speedup vs baseline: 1.9891x; 1.9891x over previous
//
#include <hip/hip_runtime.h>

// QuadPool — layout (established rounds 0-3, verified passing rounds 4-6):
//   in_sizes = element counts: [N*C f32 features][N int32 keys][P int32 plk]
//   d_out = FLOAT32, out_size = P*C + N: [pooled P*C][parent_idx N]
// pooled[p,:] = max over children whose keys>>2 maps to parent p (keys sorted ->
// contiguous segments); empty parents -> 0. parent_idx[i] = searchsorted(plk, keys[i]>>2).
//
// Round-7: revert round-6 fusion (per-wave binary search = 4000-cycle serial
// prologue per wave, +215 us). Structure = round-5's proven split, but
// qp_starts' 20-deep binary searches are replaced by an O(N) boundary
// scatter fused into the pidx kernel: thread i writes starts[p]=i for
// p in (parent(i-1), parent(i)] (avg loop length P/N ~ 0.3, no dependent
// load chains). Front kernel ~12 MB traffic ~4 us; pool unchanged.

typedef float v4f __attribute__((ext_vector_type(4)));

static __device__ __forceinline__ v4f vmax4(v4f a, v4f b) {
    v4f r;
    r.x = fmaxf(a.x, b.x); r.y = fmaxf(a.y, b.y);
    r.z = fmaxf(a.z, b.z); r.w = fmaxf(a.w, b.w);
    return r;
}

static __device__ __forceinline__ int parent_of(int key, const int* __restrict__ plk, int P) {
    const int pk = key >> 2;
    if (pk >= 0 && pk < P && plk[pk] == pk && (pk == 0 || plk[pk - 1] < pk))
        return pk;                       // plk is arange: searchsorted == pk
    int lo = 0, hi = P;                  // generic fallback
    while (lo < hi) {
        int mid = (lo + hi) >> 1;
        if (plk[mid] >= pk) hi = mid; else lo = mid + 1;
    }
    return lo;
}

// Fused: pidx write + segment-boundary scatter.
// starts[p] = first child i with parent(i) >= p; derived from adjacent-parent
// transitions (parent is nondecreasing since keys are sorted).
__global__ void qp_front(const int* __restrict__ keys, const int* __restrict__ plk,
                         float* __restrict__ pidx_out, int* __restrict__ starts,
                         int N, int P) {
    int i = blockIdx.x * blockDim.x + threadIdx.x;
    if (i >= N) return;
    const int pi = parent_of(keys[i], plk, P);
    __builtin_nontemporal_store((float)pi, pidx_out + i);
    const int pprev = (i == 0) ? -1 : parent_of(keys[i - 1], plk, P);
    for (int p = pprev + 1; p <= pi; ++p) starts[p] = i;     // avg P/N iters
    if (i == N - 1)
        for (int p = pi + 1; p <= P; ++p) starts[p] = N;     // trailing empties + sentinel
}

// One 64-lane wave per parent; lane l owns channels [4l,4l+4): 64 lanes x 16B
// = 1KB fully-coalesced row reads; every feature row read exactly once.
__global__ void __launch_bounds__(256) qp_pool(const float* __restrict__ feat,
        const int* __restrict__ starts, float* __restrict__ pooled, int P, int C) {
    int t = blockIdx.x * blockDim.x + threadIdx.x;
    int wave = t >> 6, lane = t & 63;
    if (wave >= P) return;
    const int s = starts[wave];
    const int e = starts[wave + 1];
    const int n = e - s;
    const size_t stepv = (size_t)(C >> 2);
    for (int c0 = lane * 4; c0 < C; c0 += 256) {
        const v4f* p = reinterpret_cast<const v4f*>(feat + (size_t)s * C + c0);
        v4f m; m.x = m.y = m.z = m.w = -INFINITY;
        int i = 0;
        for (; i + 2 <= n; i += 2) {                 // 2 loads in flight per wave
            v4f a = __builtin_nontemporal_load(p);
            v4f b = __builtin_nontemporal_load(p + stepv);
            p += 2 * stepv;
            m = vmax4(m, vmax4(a, b));
        }
        if (i < n) m = vmax4(m, __builtin_nontemporal_load(p));
        if (n <= 0) { m.x = m.y = m.z = m.w = 0.f; } // empty parent -> 0
        __builtin_nontemporal_store(m,
            reinterpret_cast<v4f*>(pooled + (size_t)wave * C + c0));
    }
}

extern "C" void kernel_launch(void* const* d_in, const int* in_sizes, int n_in,
                              void* d_out, int out_size, void* d_ws, size_t ws_size,
                              hipStream_t stream) {
    const float* feat = (const float*)d_in[0];
    const int*   keys = (const int*)d_in[1];
    const int*   plk  = (const int*)d_in[2];

    // Geometry (validated against out_size invariant; (1,1) is the known-true case).
    const long long F = in_sizes[0], K = in_sizes[1], L = in_sizes[2];
    int N = (int)K, P = (int)L, C = (int)(F / (K > 0 ? K : 1));
    if ((long long)P * C + N != (long long)out_size) {
        for (int w1 = 1; w1 <= 2; ++w1) {
            bool done = false;
            for (int w2 = 1; w2 <= 2; ++w2) {
                if (K % w1 || L % w2) continue;
                long long n = K / w1, p = L / w2;
                if (n <= 0 || p <= 0 || F % n) continue;
                long long c = F / n;
                if (p * c + n == (long long)out_size) {
                    N = (int)n; P = (int)p; C = (int)c; done = true; break;
                }
            }
            if (done) break;
        }
    }

    float* outf   = (float*)d_out;
    float* pooled = outf;                     // [P*C] f32
    float* pidx   = outf + (size_t)P * C;     // [N]   f32
    int* starts   = (int*)d_ws;               // (P+1) ints

    const int tb = 256;
    qp_front<<<(N + tb - 1) / tb, tb, 0, stream>>>(keys, plk, pidx, starts, N, P);
    const long long thr = (long long)P * 64;
    qp_pool<<<(int)((thr + tb - 1) / tb), tb, 0, stream>>>(feat, starts, pooled, P, C);
}